// Round 1
// baseline (443.737 us; speedup 1.0000x reference)
//
#include <hip/hip_runtime.h>
#include <math.h>

#define NEG 0.2f

__device__ __forceinline__ float lrelu(float x){ return x > 0.f ? x : NEG*x; }

// ---- detect whether edge_index is int64 (odd 32-bit words all zero) or int32 ----
__global__ void detect_kernel(const int* __restrict__ ei, int* __restrict__ flag){
  int lane = threadIdx.x;                 // 64 threads, 1 block
  int v = ei[2*lane + 1];
  unsigned long long b = __ballot(v != 0);
  if (lane == 0) flag[0] = (b == 0ULL) ? 1 : 0;   // 1 => int64 layout
}

__global__ void count_kernel(const int* __restrict__ ei, const int* __restrict__ flag,
                             int* __restrict__ counts, int E){
  int is64 = flag[0];
  int stride = gridDim.x * blockDim.x;
  for (int i = blockIdx.x*blockDim.x + threadIdx.x; i < E; i += stride){
    int d = is64 ? ei[2*(E + i)] : ei[E + i];
    atomicAdd(&counts[d], 1);
  }
}

__global__ void fill_kernel(const int* __restrict__ ei, const int* __restrict__ flag,
                            int* __restrict__ cursor, int* __restrict__ adj, int E){
  int is64 = flag[0];
  int stride = gridDim.x * blockDim.x;
  for (int i = blockIdx.x*blockDim.x + threadIdx.x; i < E; i += stride){
    int s = is64 ? ei[2*i]       : ei[i];
    int d = is64 ? ei[2*(E + i)] : ei[E + i];
    int pos = atomicAdd(&cursor[d], 1);
    adj[pos] = s;
  }
}

// ---- single-block hierarchical exclusive scan: offs[0]=0, offs[i+1]=sum counts[0..i] ----
__global__ void scan_kernel(const int* __restrict__ counts, int* __restrict__ offs, int n){
  __shared__ int wsum[16];
  __shared__ int carry_s;
  int t = threadIdx.x, lane = t & 63, w = t >> 6;
  if (t == 0){ carry_s = 0; offs[0] = 0; }
  __syncthreads();
  for (int base = 0; base < n; base += 1024){
    int i = base + t;
    int x = (i < n) ? counts[i] : 0;
    #pragma unroll
    for (int off = 1; off < 64; off <<= 1){
      int y = __shfl_up(x, off, 64);
      if (lane >= off) x += y;
    }
    if (lane == 63) wsum[w] = x;
    __syncthreads();
    if (t < 16){
      int y = wsum[t];
      #pragma unroll
      for (int off = 1; off < 16; off <<= 1){
        int z = __shfl_up(y, off, 64);
        if (t >= off) y += z;
      }
      wsum[t] = y;
    }
    __syncthreads();
    int pre = (w > 0) ? wsum[w-1] : 0;
    int incl = x + pre + carry_s;
    if (i < n) offs[i + 1] = incl;
    __syncthreads();
    if (t == 1023) carry_s = incl;
    __syncthreads();
  }
}

// ---- GEMM1: h1 = x @ W1  [N,128]x[128,256], fused alpha_src1/alpha_dst1 ----
__global__ void gemm1_kernel(const float* __restrict__ x, const float* __restrict__ W,
                             const float* __restrict__ asrc, const float* __restrict__ adst,
                             float* __restrict__ h1, float* __restrict__ as1,
                             float* __restrict__ ad1){
  __shared__ float a_s[16][132];
  int t = threadIdx.x;
  int row0 = blockIdx.x * 16;
  const float4* xv = reinterpret_cast<const float4*>(x + (size_t)row0 * 128);
  #pragma unroll
  for (int i = t; i < 512; i += 256){
    int r = i >> 5, j = i & 31;
    float4 v = xv[(size_t)r*32 + j];
    *reinterpret_cast<float4*>(&a_s[r][j*4]) = v;
  }
  __syncthreads();
  float acc[16];
  #pragma unroll
  for (int r = 0; r < 16; r++) acc[r] = 0.f;
  int col = t;
  #pragma unroll 4
  for (int k = 0; k < 128; k++){
    float b = W[k*256 + col];
    #pragma unroll
    for (int r = 0; r < 16; r++) acc[r] = fmaf(a_s[r][k], b, acc[r]);
  }
  #pragma unroll
  for (int r = 0; r < 16; r++) h1[(size_t)(row0 + r)*256 + col] = acc[r];
  // fused alpha: wave w == head (256 threads = 4 waves = 4 heads), lane == channel
  float av = asrc[col], dv = adst[col];
  int lane = t & 63, head = t >> 6;
  #pragma unroll
  for (int r = 0; r < 16; r++){
    float ps = acc[r]*av, pd = acc[r]*dv;
    #pragma unroll
    for (int off = 32; off; off >>= 1){
      ps += __shfl_xor(ps, off, 64);
      pd += __shfl_xor(pd, off, 64);
    }
    if (lane == 0){
      as1[(row0 + r)*4 + head] = ps;
      ad1[(row0 + r)*4 + head] = pd;
    }
  }
}

// ---- layer-1 aggregation: wave per dst node, online per-head softmax, fused bias+ELU ----
__global__ void agg1_kernel(const float* __restrict__ h1, const float* __restrict__ as1,
                            const float* __restrict__ ad1, const float* __restrict__ b1,
                            const int* __restrict__ offs, const int* __restrict__ adj,
                            float* __restrict__ hact, int N){
  int node = (blockIdx.x*blockDim.x + threadIdx.x) >> 6;
  int lane = threadIdx.x & 63;
  if (node >= N) return;
  int beg = offs[node], end = offs[node + 1];
  float4 adv4 = *reinterpret_cast<const float4*>(ad1 + (size_t)node*4);
  float adv[4] = {adv4.x, adv4.y, adv4.z, adv4.w};
  // pass 1: per-head max (lanes stride edges)
  float m[4] = {-1e30f, -1e30f, -1e30f, -1e30f};
  for (int i = beg + lane; i < end; i += 64){
    int src = adj[i];
    float4 sv = *reinterpret_cast<const float4*>(as1 + (size_t)src*4);
    float s4[4] = {sv.x, sv.y, sv.z, sv.w};
    #pragma unroll
    for (int h = 0; h < 4; h++) m[h] = fmaxf(m[h], lrelu(s4[h] + adv[h]));
  }
  {   // self loop (every lane, identical value)
    float4 sv = *reinterpret_cast<const float4*>(as1 + (size_t)node*4);
    float s4[4] = {sv.x, sv.y, sv.z, sv.w};
    #pragma unroll
    for (int h = 0; h < 4; h++) m[h] = fmaxf(m[h], lrelu(s4[h] + adv[h]));
  }
  #pragma unroll
  for (int off = 32; off; off >>= 1){
    #pragma unroll
    for (int h = 0; h < 4; h++) m[h] = fmaxf(m[h], __shfl_xor(m[h], off, 64));
  }
  // pass 2: exp-sum + weighted accumulate (whole wave per edge; lane = channel)
  float s[4] = {0,0,0,0}, acc[4] = {0,0,0,0};
  for (int i = beg; i < end; ++i){
    int src = adj[i];
    float4 sv = *reinterpret_cast<const float4*>(as1 + (size_t)src*4);
    float s4[4] = {sv.x, sv.y, sv.z, sv.w};
    const float* hr = h1 + (size_t)src*256;
    #pragma unroll
    for (int k = 0; k < 4; k++){
      float ex = expf(lrelu(s4[k] + adv[k]) - m[k]);
      s[k] += ex;
      acc[k] = fmaf(ex, hr[k*64 + lane], acc[k]);
    }
  }
  {   // self loop
    float4 sv = *reinterpret_cast<const float4*>(as1 + (size_t)node*4);
    float s4[4] = {sv.x, sv.y, sv.z, sv.w};
    const float* hr = h1 + (size_t)node*256;
    #pragma unroll
    for (int k = 0; k < 4; k++){
      float ex = expf(lrelu(s4[k] + adv[k]) - m[k]);
      s[k] += ex;
      acc[k] = fmaf(ex, hr[k*64 + lane], acc[k]);
    }
  }
  #pragma unroll
  for (int k = 0; k < 4; k++){
    float v = acc[k] / (s[k] + 1e-16f) + b1[k*64 + lane];
    v = v > 0.f ? v : expm1f(v);          // ELU (alpha=1)
    hact[(size_t)node*256 + k*64 + lane] = v;
  }
}

// ---- GEMM2: h2 = hact @ W2  [N,256]x[256,16], fused alpha_src2/alpha_dst2 ----
__global__ void gemm2_kernel(const float* __restrict__ hact, const float* __restrict__ W2,
                             const float* __restrict__ asrc, const float* __restrict__ adst,
                             float* __restrict__ h2, float* __restrict__ as2,
                             float* __restrict__ ad2){
  __shared__ float a_s[16][260];
  __shared__ float w_s[256*16];
  int t = threadIdx.x;
  int row0 = blockIdx.x * 16;
  for (int i = t; i < 1024; i += 256)
    reinterpret_cast<float4*>(w_s)[i] = reinterpret_cast<const float4*>(W2)[i];
  const float4* hv = reinterpret_cast<const float4*>(hact + (size_t)row0 * 256);
  for (int i = t; i < 1024; i += 256){
    int r = i >> 6, j = i & 63;
    *reinterpret_cast<float4*>(&a_s[r][j*4]) = hv[(size_t)r*64 + j];
  }
  __syncthreads();
  int r = t >> 4, c = t & 15;
  float acc = 0.f;
  #pragma unroll 4
  for (int k = 0; k < 256; k++) acc = fmaf(a_s[r][k], w_s[k*16 + c], acc);
  int node = row0 + r;
  h2[(size_t)node*16 + c] = acc;
  float ps = acc * asrc[c], pd = acc * adst[c];
  #pragma unroll
  for (int off = 1; off < 16; off <<= 1){
    ps += __shfl_xor(ps, off, 64);
    pd += __shfl_xor(pd, off, 64);
  }
  if (c == 0){ as2[node] = ps; ad2[node] = pd; }
}

// ---- layer-2 aggregation: wave per node (4 edge-groups x 16 channels), fused bias+log_softmax ----
__global__ void agg2_kernel(const float* __restrict__ h2, const float* __restrict__ as2,
                            const float* __restrict__ ad2, const float* __restrict__ b2,
                            const int* __restrict__ offs, const int* __restrict__ adj,
                            float* __restrict__ out, int N){
  int node = (blockIdx.x*blockDim.x + threadIdx.x) >> 6;
  int lane = threadIdx.x & 63;
  if (node >= N) return;
  int beg = offs[node], end = offs[node + 1];
  float adn = ad2[node];
  float m = -1e30f;
  for (int i = beg + lane; i < end; i += 64)
    m = fmaxf(m, lrelu(as2[adj[i]] + adn));
  float eself = lrelu(as2[node] + adn);
  m = fmaxf(m, eself);
  #pragma unroll
  for (int off = 32; off; off >>= 1) m = fmaxf(m, __shfl_xor(m, off, 64));
  int g = lane >> 4, c = lane & 15;
  float s = 0.f, acc = 0.f;
  for (int i = beg + g; i < end; i += 4){
    int src = adj[i];
    float ex = expf(lrelu(as2[src] + adn) - m);
    s += ex;
    acc = fmaf(ex, h2[(size_t)src*16 + c], acc);
  }
  if (g == 0){
    float ex = expf(eself - m);
    s += ex;
    acc = fmaf(ex, h2[(size_t)node*16 + c], acc);
  }
  acc += __shfl_xor(acc, 16, 64); acc += __shfl_xor(acc, 32, 64);
  s   += __shfl_xor(s,   16, 64); s   += __shfl_xor(s,   32, 64);
  float v = acc / (s + 1e-16f) + b2[c];
  // log_softmax over the 16 channels (replicated identically in each 16-lane group)
  float mx = v;
  #pragma unroll
  for (int off = 1; off < 16; off <<= 1) mx = fmaxf(mx, __shfl_xor(mx, off, 64));
  float se = expf(v - mx);
  #pragma unroll
  for (int off = 1; off < 16; off <<= 1) se += __shfl_xor(se, off, 64);
  float o = v - mx - logf(se);
  if (lane < 16) out[(size_t)node*16 + c] = o;
}

extern "C" void kernel_launch(void* const* d_in, const int* in_sizes, int n_in,
                              void* d_out, int out_size, void* d_ws, size_t ws_size,
                              hipStream_t stream){
  const float* x    = (const float*)d_in[0];
  const int*   ei   = (const int*)d_in[1];
  const float* W1   = (const float*)d_in[2];
  const float* as1w = (const float*)d_in[3];
  const float* ad1w = (const float*)d_in[4];
  const float* b1   = (const float*)d_in[5];
  const float* W2   = (const float*)d_in[6];
  const float* as2w = (const float*)d_in[7];
  const float* ad2w = (const float*)d_in[8];
  const float* b2   = (const float*)d_in[9];
  float* out = (float*)d_out;

  int N = in_sizes[0] / 128;   // 50000
  int E = in_sizes[1] / 2;     // 800000 (element count same for int32/int64)

  char* p = (char*)d_ws;
  size_t off = 0;
  auto alloc = [&](size_t b){ size_t c = off; off = (off + b + 255) & ~(size_t)255; return c; };
  float* h1     = (float*)(p + alloc((size_t)N*256*4));   // 51.2 MB
  float* hact   = (float*)(p + alloc((size_t)N*256*4));   // 51.2 MB
  float* h2     = (float*)(p + alloc((size_t)N*16*4));    // 3.2 MB
  float* as1    = (float*)(p + alloc((size_t)N*4*4));
  float* ad1    = (float*)(p + alloc((size_t)N*4*4));
  float* as2    = (float*)(p + alloc((size_t)N*4));
  float* ad2    = (float*)(p + alloc((size_t)N*4));
  int*   counts = (int*)(p + alloc((size_t)N*4));
  int*   offs   = (int*)(p + alloc((size_t)(N+1)*4));
  int*   cursor = (int*)(p + alloc((size_t)N*4));
  int*   adj    = (int*)(p + alloc((size_t)E*4));         // 3.2 MB
  int*   flag   = (int*)(p + alloc(4));
  // total ~111.5 MB of d_ws

  hipMemsetAsync(counts, 0, (size_t)N*4, stream);
  detect_kernel<<<1, 64, 0, stream>>>(ei, flag);
  count_kernel<<<2048, 256, 0, stream>>>(ei, flag, counts, E);
  scan_kernel<<<1, 1024, 0, stream>>>(counts, offs, N);
  hipMemcpyAsync(cursor, offs, (size_t)N*4, hipMemcpyDeviceToDevice, stream);
  fill_kernel<<<2048, 256, 0, stream>>>(ei, flag, cursor, adj, E);

  gemm1_kernel<<<N/16, 256, 0, stream>>>(x, W1, as1w, ad1w, h1, as1, ad1);
  agg1_kernel<<<(N*64 + 255)/256, 256, 0, stream>>>(h1, as1, ad1, b1, offs, adj, hact, N);
  gemm2_kernel<<<N/16, 256, 0, stream>>>(hact, W2, as2w, ad2w, h2, as2, ad2);
  agg2_kernel<<<(N*64 + 255)/256, 256, 0, stream>>>(h2, as2, ad2, b2, offs, adj, out, N);
}

// Round 2
// 421.061 us; speedup vs baseline: 1.0539x; 1.0539x over previous
//
#include <hip/hip_runtime.h>
#include <math.h>

#define NEG 0.2f

__device__ __forceinline__ float lrelu(float x){ return x > 0.f ? x : NEG*x; }

__device__ __forceinline__ float rl(float x, int j){
  return __uint_as_float((unsigned)__builtin_amdgcn_readlane((int)__float_as_uint(x), j));
}

// select a0..a3 by head index encoded in (b4,b5) = (lane&16, lane&32)
__device__ __forceinline__ float selh(float a0, float a1, float a2, float a3,
                                      bool b4, bool b5){
  float lo = b4 ? a1 : a0;
  float hi = b4 ? a3 : a2;
  return b5 ? hi : lo;
}

// ---- detect whether edge_index is int64 (odd 32-bit words all zero) or int32 ----
__global__ void detect_kernel(const int* __restrict__ ei, int* __restrict__ flag){
  int lane = threadIdx.x;                 // 64 threads, 1 block
  int v = ei[2*lane + 1];
  unsigned long long b = __ballot(v != 0);
  if (lane == 0) flag[0] = (b == 0ULL) ? 1 : 0;   // 1 => int64 layout
}

__global__ void count_kernel(const int* __restrict__ ei, const int* __restrict__ flag,
                             int* __restrict__ counts, int E){
  int is64 = flag[0];
  int stride = gridDim.x * blockDim.x;
  for (int i = blockIdx.x*blockDim.x + threadIdx.x; i < E; i += stride){
    int d = is64 ? ei[2*(E + i)] : ei[E + i];
    atomicAdd(&counts[d], 1);
  }
}

__global__ void fill_kernel(const int* __restrict__ ei, const int* __restrict__ flag,
                            int* __restrict__ cursor, int* __restrict__ adj, int E){
  int is64 = flag[0];
  int stride = gridDim.x * blockDim.x;
  for (int i = blockIdx.x*blockDim.x + threadIdx.x; i < E; i += stride){
    int s = is64 ? ei[2*i]       : ei[i];
    int d = is64 ? ei[2*(E + i)] : ei[E + i];
    int pos = atomicAdd(&cursor[d], 1);
    adj[pos] = s;
  }
}

// ---- single-block hierarchical exclusive scan: offs[0]=0, offs[i+1]=sum counts[0..i] ----
__global__ void scan_kernel(const int* __restrict__ counts, int* __restrict__ offs, int n){
  __shared__ int wsum[16];
  __shared__ int carry_s;
  int t = threadIdx.x, lane = t & 63, w = t >> 6;
  if (t == 0){ carry_s = 0; offs[0] = 0; }
  __syncthreads();
  for (int base = 0; base < n; base += 1024){
    int i = base + t;
    int x = (i < n) ? counts[i] : 0;
    #pragma unroll
    for (int off = 1; off < 64; off <<= 1){
      int y = __shfl_up(x, off, 64);
      if (lane >= off) x += y;
    }
    if (lane == 63) wsum[w] = x;
    __syncthreads();
    if (t < 16){
      int y = wsum[t];
      #pragma unroll
      for (int off = 1; off < 16; off <<= 1){
        int z = __shfl_up(y, off, 64);
        if (t >= off) y += z;
      }
      wsum[t] = y;
    }
    __syncthreads();
    int pre = (w > 0) ? wsum[w-1] : 0;
    int incl = x + pre + carry_s;
    if (i < n) offs[i + 1] = incl;
    __syncthreads();
    if (t == 1023) carry_s = incl;
    __syncthreads();
  }
}

// ---- GEMM1: h1 = x @ W1  [N,128]x[128,256], fused alpha_src1/alpha_dst1 ----
__global__ void gemm1_kernel(const float* __restrict__ x, const float* __restrict__ W,
                             const float* __restrict__ asrc, const float* __restrict__ adst,
                             float* __restrict__ h1, float* __restrict__ as1,
                             float* __restrict__ ad1){
  __shared__ float a_s[16][132];
  int t = threadIdx.x;
  int row0 = blockIdx.x * 16;
  const float4* xv = reinterpret_cast<const float4*>(x + (size_t)row0 * 128);
  #pragma unroll
  for (int i = t; i < 512; i += 256){
    int r = i >> 5, j = i & 31;
    float4 v = xv[(size_t)r*32 + j];
    *reinterpret_cast<float4*>(&a_s[r][j*4]) = v;
  }
  __syncthreads();
  float acc[16];
  #pragma unroll
  for (int r = 0; r < 16; r++) acc[r] = 0.f;
  int col = t;
  #pragma unroll 4
  for (int k = 0; k < 128; k++){
    float b = W[k*256 + col];
    #pragma unroll
    for (int r = 0; r < 16; r++) acc[r] = fmaf(a_s[r][k], b, acc[r]);
  }
  #pragma unroll
  for (int r = 0; r < 16; r++) h1[(size_t)(row0 + r)*256 + col] = acc[r];
  // fused alpha: wave w == head (256 threads = 4 waves = 4 heads), lane == channel
  float av = asrc[col], dv = adst[col];
  int lane = t & 63, head = t >> 6;
  #pragma unroll
  for (int r = 0; r < 16; r++){
    float ps = acc[r]*av, pd = acc[r]*dv;
    #pragma unroll
    for (int off = 32; off; off >>= 1){
      ps += __shfl_xor(ps, off, 64);
      pd += __shfl_xor(pd, off, 64);
    }
    if (lane == 0){
      as1[(row0 + r)*4 + head] = ps;
      ad1[(row0 + r)*4 + head] = pd;
    }
  }
}

// ---- layer-1 aggregation: wave per dst node, ONLINE softmax, edge-parallel exp,
//      readlane broadcast, float4 gather; fused bias+ELU ----
__global__ void agg1_kernel(const float* __restrict__ h1, const float* __restrict__ as1,
                            const float* __restrict__ ad1, const float* __restrict__ b1,
                            const int* __restrict__ offs, const int* __restrict__ adj,
                            float* __restrict__ hact, int N){
  int node = (blockIdx.x*blockDim.x + threadIdx.x) >> 6;
  int lane = threadIdx.x & 63;
  if (node >= N) return;
  int beg = offs[node], end = offs[node + 1];
  bool b4 = (lane & 16) != 0, b5 = (lane & 32) != 0;   // head = lane>>4

  float4 adv4 = *reinterpret_cast<const float4*>(ad1 + (size_t)node*4);
  float adv[4] = {adv4.x, adv4.y, adv4.z, adv4.w};
  float4 sv4 = *reinterpret_cast<const float4*>(as1 + (size_t)node*4);
  float svv[4] = {sv4.x, sv4.y, sv4.z, sv4.w};

  float es[4], m[4], sp[4];
  #pragma unroll
  for (int k = 0; k < 4; k++){
    es[k] = lrelu(svv[k] + adv[k]);   // self-loop logit
    m[k] = es[k];                     // running max init
    sp[k] = 0.f;                      // per-lane partial sum of exp
  }
  float4 acc = make_float4(0.f, 0.f, 0.f, 0.f);

  for (int base = beg; base < end; base += 64){
    int i = base + lane;
    bool val = i < end;
    int srcl = val ? adj[i] : 0;
    float4 av4 = *reinterpret_cast<const float4*>(as1 + (size_t)srcl*4);
    float e[4] = {av4.x, av4.y, av4.z, av4.w};
    #pragma unroll
    for (int k = 0; k < 4; k++) e[k] = val ? lrelu(e[k] + adv[k]) : -3e38f;

    // chunk max + online rescale
    float sc[4];
    #pragma unroll
    for (int k = 0; k < 4; k++){
      float cm = e[k];
      #pragma unroll
      for (int off = 32; off; off >>= 1) cm = fmaxf(cm, __shfl_xor(cm, off, 64));
      float nm = fmaxf(m[k], cm);
      sc[k] = __expf(m[k] - nm);
      m[k] = nm;
      sp[k] *= sc[k];
    }
    float sch = selh(sc[0], sc[1], sc[2], sc[3], b4, b5);
    acc.x *= sch; acc.y *= sch; acc.z *= sch; acc.w *= sch;

    // per-edge exp computed ONCE (lane-parallel over edges)
    float ex[4];
    #pragma unroll
    for (int k = 0; k < 4; k++){
      ex[k] = __expf(e[k] - m[k]);    // invalid lanes: exp(-huge) -> 0
      sp[k] += ex[k];
    }

    // broadcast phase: readlane weights, float4 gather of h1[src]
    int cnt = end - base; if (cnt > 64) cnt = 64;
    for (int j = 0; j < cnt; j++){
      int srcj = __builtin_amdgcn_readlane(srcl, j);
      float e0 = rl(ex[0], j), e1 = rl(ex[1], j);
      float e2 = rl(ex[2], j), e3 = rl(ex[3], j);
      float eh = selh(e0, e1, e2, e3, b4, b5);
      float4 hv = *reinterpret_cast<const float4*>(h1 + (size_t)srcj*256 + lane*4);
      acc.x = fmaf(eh, hv.x, acc.x);
      acc.y = fmaf(eh, hv.y, acc.y);
      acc.z = fmaf(eh, hv.z, acc.z);
      acc.w = fmaf(eh, hv.w, acc.w);
    }
  }

  // total denominator per head
  #pragma unroll
  for (int k = 0; k < 4; k++){
    #pragma unroll
    for (int off = 32; off; off >>= 1) sp[k] += __shfl_xor(sp[k], off, 64);
  }
  // self-loop contribution
  float exs[4];
  #pragma unroll
  for (int k = 0; k < 4; k++){
    exs[k] = __expf(es[k] - m[k]);
    sp[k] += exs[k];
  }
  float ehs = selh(exs[0], exs[1], exs[2], exs[3], b4, b5);
  float4 hv = *reinterpret_cast<const float4*>(h1 + (size_t)node*256 + lane*4);
  acc.x = fmaf(ehs, hv.x, acc.x);
  acc.y = fmaf(ehs, hv.y, acc.y);
  acc.z = fmaf(ehs, hv.z, acc.z);
  acc.w = fmaf(ehs, hv.w, acc.w);

  float dh = selh(sp[0], sp[1], sp[2], sp[3], b4, b5) + 1e-16f;
  float rinv = 1.0f / dh;
  float4 bv = *reinterpret_cast<const float4*>(b1 + lane*4);
  float4 o;
  o.x = acc.x*rinv + bv.x;
  o.y = acc.y*rinv + bv.y;
  o.z = acc.z*rinv + bv.z;
  o.w = acc.w*rinv + bv.w;
  o.x = o.x > 0.f ? o.x : expm1f(o.x);
  o.y = o.y > 0.f ? o.y : expm1f(o.y);
  o.z = o.z > 0.f ? o.z : expm1f(o.z);
  o.w = o.w > 0.f ? o.w : expm1f(o.w);
  *reinterpret_cast<float4*>(hact + (size_t)node*256 + lane*4) = o;
}

// ---- GEMM2: h2 = hact @ W2  [N,256]x[256,16], fused alpha_src2/alpha_dst2 ----
__global__ void gemm2_kernel(const float* __restrict__ hact, const float* __restrict__ W2,
                             const float* __restrict__ asrc, const float* __restrict__ adst,
                             float* __restrict__ h2, float* __restrict__ as2,
                             float* __restrict__ ad2){
  __shared__ float a_s[16][260];
  __shared__ float w_s[256*16];
  int t = threadIdx.x;
  int row0 = blockIdx.x * 16;
  for (int i = t; i < 1024; i += 256)
    reinterpret_cast<float4*>(w_s)[i] = reinterpret_cast<const float4*>(W2)[i];
  const float4* hv = reinterpret_cast<const float4*>(hact + (size_t)row0 * 256);
  for (int i = t; i < 1024; i += 256){
    int r = i >> 6, j = i & 63;
    *reinterpret_cast<float4*>(&a_s[r][j*4]) = hv[(size_t)r*64 + j];
  }
  __syncthreads();
  int r = t >> 4, c = t & 15;
  float acc = 0.f;
  #pragma unroll 4
  for (int k = 0; k < 256; k++) acc = fmaf(a_s[r][k], w_s[k*16 + c], acc);
  int node = row0 + r;
  h2[(size_t)node*16 + c] = acc;
  float ps = acc * asrc[c], pd = acc * adst[c];
  #pragma unroll
  for (int off = 1; off < 16; off <<= 1){
    ps += __shfl_xor(ps, off, 64);
    pd += __shfl_xor(pd, off, 64);
  }
  if (c == 0){ as2[node] = ps; ad2[node] = pd; }
}

// ---- layer-2 aggregation: wave per node (4 edge-groups x 16 channels), fused bias+log_softmax ----
__global__ void agg2_kernel(const float* __restrict__ h2, const float* __restrict__ as2,
                            const float* __restrict__ ad2, const float* __restrict__ b2,
                            const int* __restrict__ offs, const int* __restrict__ adj,
                            float* __restrict__ out, int N){
  int node = (blockIdx.x*blockDim.x + threadIdx.x) >> 6;
  int lane = threadIdx.x & 63;
  if (node >= N) return;
  int beg = offs[node], end = offs[node + 1];
  float adn = ad2[node];
  float m = -1e30f;
  for (int i = beg + lane; i < end; i += 64)
    m = fmaxf(m, lrelu(as2[adj[i]] + adn));
  float eself = lrelu(as2[node] + adn);
  m = fmaxf(m, eself);
  #pragma unroll
  for (int off = 32; off; off >>= 1) m = fmaxf(m, __shfl_xor(m, off, 64));
  int g = lane >> 4, c = lane & 15;
  float s = 0.f, acc = 0.f;
  for (int i = beg + g; i < end; i += 4){
    int src = adj[i];
    float ex = __expf(lrelu(as2[src] + adn) - m);
    s += ex;
    acc = fmaf(ex, h2[(size_t)src*16 + c], acc);
  }
  if (g == 0){
    float ex = __expf(eself - m);
    s += ex;
    acc = fmaf(ex, h2[(size_t)node*16 + c], acc);
  }
  acc += __shfl_xor(acc, 16, 64); acc += __shfl_xor(acc, 32, 64);
  s   += __shfl_xor(s,   16, 64); s   += __shfl_xor(s,   32, 64);
  float v = acc / (s + 1e-16f) + b2[c];
  // log_softmax over the 16 channels (replicated identically in each 16-lane group)
  float mx = v;
  #pragma unroll
  for (int off = 1; off < 16; off <<= 1) mx = fmaxf(mx, __shfl_xor(mx, off, 64));
  float se = expf(v - mx);
  #pragma unroll
  for (int off = 1; off < 16; off <<= 1) se += __shfl_xor(se, off, 64);
  float o = v - mx - logf(se);
  if (lane < 16) out[(size_t)node*16 + c] = o;
}

extern "C" void kernel_launch(void* const* d_in, const int* in_sizes, int n_in,
                              void* d_out, int out_size, void* d_ws, size_t ws_size,
                              hipStream_t stream){
  const float* x    = (const float*)d_in[0];
  const int*   ei   = (const int*)d_in[1];
  const float* W1   = (const float*)d_in[2];
  const float* as1w = (const float*)d_in[3];
  const float* ad1w = (const float*)d_in[4];
  const float* b1   = (const float*)d_in[5];
  const float* W2   = (const float*)d_in[6];
  const float* as2w = (const float*)d_in[7];
  const float* ad2w = (const float*)d_in[8];
  const float* b2   = (const float*)d_in[9];
  float* out = (float*)d_out;

  int N = in_sizes[0] / 128;   // 50000
  int E = in_sizes[1] / 2;     // 800000 (element count same for int32/int64)

  char* p = (char*)d_ws;
  size_t off = 0;
  auto alloc = [&](size_t b){ size_t c = off; off = (off + b + 255) & ~(size_t)255; return c; };
  float* h1     = (float*)(p + alloc((size_t)N*256*4));   // 51.2 MB
  float* hact   = (float*)(p + alloc((size_t)N*256*4));   // 51.2 MB
  float* h2     = (float*)(p + alloc((size_t)N*16*4));    // 3.2 MB
  float* as1    = (float*)(p + alloc((size_t)N*4*4));
  float* ad1    = (float*)(p + alloc((size_t)N*4*4));
  float* as2    = (float*)(p + alloc((size_t)N*4));
  float* ad2    = (float*)(p + alloc((size_t)N*4));
  int*   counts = (int*)(p + alloc((size_t)N*4));
  int*   offs   = (int*)(p + alloc((size_t)(N+1)*4));
  int*   cursor = (int*)(p + alloc((size_t)N*4));
  int*   adj    = (int*)(p + alloc((size_t)E*4));         // 3.2 MB
  int*   flag   = (int*)(p + alloc(4));

  hipMemsetAsync(counts, 0, (size_t)N*4, stream);
  detect_kernel<<<1, 64, 0, stream>>>(ei, flag);
  count_kernel<<<2048, 256, 0, stream>>>(ei, flag, counts, E);
  scan_kernel<<<1, 1024, 0, stream>>>(counts, offs, N);
  hipMemcpyAsync(cursor, offs, (size_t)N*4, hipMemcpyDeviceToDevice, stream);
  fill_kernel<<<2048, 256, 0, stream>>>(ei, flag, cursor, adj, E);

  gemm1_kernel<<<N/16, 256, 0, stream>>>(x, W1, as1w, ad1w, h1, as1, ad1);
  agg1_kernel<<<(N*64 + 255)/256, 256, 0, stream>>>(h1, as1, ad1, b1, offs, adj, hact, N);
  gemm2_kernel<<<N/16, 256, 0, stream>>>(hact, W2, as2w, ad2w, h2, as2, ad2);
  agg2_kernel<<<(N*64 + 255)/256, 256, 0, stream>>>(h2, as2, ad2, b2, offs, adj, out, N);
}

// Round 3
// 339.609 us; speedup vs baseline: 1.3066x; 1.2398x over previous
//
#include <hip/hip_runtime.h>
#include <math.h>

#define NEG 0.2f

__device__ __forceinline__ float lrelu(float x){ return x > 0.f ? x : NEG*x; }

__device__ __forceinline__ float rl(float x, int j){
  return __uint_as_float((unsigned)__builtin_amdgcn_readlane((int)__float_as_uint(x), j));
}

// select a0..a3 by head index encoded in (b4,b5) = (lane&16, lane&32)
__device__ __forceinline__ float selh(float a0, float a1, float a2, float a3,
                                      bool b4, bool b5){
  float lo = b4 ? a1 : a0;
  float hi = b4 ? a3 : a2;
  return b5 ? hi : lo;
}

__device__ __forceinline__ unsigned short f2bf(float x){
  unsigned u = __float_as_uint(x);
  u += 0x7fffu + ((u >> 16) & 1u);     // RNE
  return (unsigned short)(u >> 16);
}

// ---- detect whether edge_index is int64 (odd 32-bit words all zero) or int32 ----
__global__ void detect_kernel(const int* __restrict__ ei, int* __restrict__ flag){
  int lane = threadIdx.x;                 // 64 threads, 1 block
  int v = ei[2*lane + 1];
  unsigned long long b = __ballot(v != 0);
  if (lane == 0) flag[0] = (b == 0ULL) ? 1 : 0;   // 1 => int64 layout
}

__global__ void count_kernel(const int* __restrict__ ei, const int* __restrict__ flag,
                             int* __restrict__ counts, int E){
  int is64 = flag[0];
  int stride = gridDim.x * blockDim.x;
  for (int i = blockIdx.x*blockDim.x + threadIdx.x; i < E; i += stride){
    int d = is64 ? ei[2*(E + i)] : ei[E + i];
    atomicAdd(&counts[d], 1);
  }
}

// ---- parallel segment assignment: no ordered prefix sum needed for CSR ----
__global__ void assign_kernel(const int* __restrict__ counts, int* __restrict__ beg,
                              int* __restrict__ cursor, int* __restrict__ totalCtr, int n){
  int i = blockIdx.x*blockDim.x + threadIdx.x;
  if (i < n){
    int c = counts[i];
    int b = atomicAdd(totalCtr, c);
    beg[i] = b;
    cursor[i] = b;
  }
}

__global__ void fill_kernel(const int* __restrict__ ei, const int* __restrict__ flag,
                            int* __restrict__ cursor, int* __restrict__ adj, int E){
  int is64 = flag[0];
  int stride = gridDim.x * blockDim.x;
  for (int i = blockIdx.x*blockDim.x + threadIdx.x; i < E; i += stride){
    int s = is64 ? ei[2*i]       : ei[i];
    int d = is64 ? ei[2*(E + i)] : ei[E + i];
    int pos = atomicAdd(&cursor[d], 1);
    adj[pos] = s;
  }
}

// ---- GEMM1: h1 = x @ W1  [N,128]x[128,256] -> bf16 store, fused fp32 alphas ----
__global__ void gemm1_kernel(const float* __restrict__ x, const float* __restrict__ W,
                             const float* __restrict__ asrc, const float* __restrict__ adst,
                             unsigned short* __restrict__ h1b, float* __restrict__ as1,
                             float* __restrict__ ad1){
  __shared__ float a_s[16][132];
  int t = threadIdx.x;
  int row0 = blockIdx.x * 16;
  const float4* xv = reinterpret_cast<const float4*>(x + (size_t)row0 * 128);
  #pragma unroll
  for (int i = t; i < 512; i += 256){
    int r = i >> 5, j = i & 31;
    float4 v = xv[(size_t)r*32 + j];
    *reinterpret_cast<float4*>(&a_s[r][j*4]) = v;
  }
  __syncthreads();
  float acc[16];
  #pragma unroll
  for (int r = 0; r < 16; r++) acc[r] = 0.f;
  int col = t;
  #pragma unroll 4
  for (int k = 0; k < 128; k++){
    float b = W[k*256 + col];
    #pragma unroll
    for (int r = 0; r < 16; r++) acc[r] = fmaf(a_s[r][k], b, acc[r]);
  }
  #pragma unroll
  for (int r = 0; r < 16; r++) h1b[(size_t)(row0 + r)*256 + col] = f2bf(acc[r]);
  // fused alpha: wave w == head (256 threads = 4 waves = 4 heads), lane == channel
  float av = asrc[col], dv = adst[col];
  int lane = t & 63, head = t >> 6;
  #pragma unroll
  for (int r = 0; r < 16; r++){
    float ps = acc[r]*av, pd = acc[r]*dv;
    #pragma unroll
    for (int off = 32; off; off >>= 1){
      ps += __shfl_xor(ps, off, 64);
      pd += __shfl_xor(pd, off, 64);
    }
    if (lane == 0){
      as1[(row0 + r)*4 + head] = ps;
      ad1[(row0 + r)*4 + head] = pd;
    }
  }
}

// ---- layer-1 aggregation: wave per dst node, online softmax, bf16 h1 gather ----
__global__ void agg1_kernel(const unsigned short* __restrict__ h1b,
                            const float* __restrict__ as1,
                            const float* __restrict__ ad1, const float* __restrict__ b1,
                            const int* __restrict__ beg, const int* __restrict__ counts,
                            const int* __restrict__ adj,
                            float* __restrict__ hact, int N){
  int node = (blockIdx.x*blockDim.x + threadIdx.x) >> 6;
  int lane = threadIdx.x & 63;
  if (node >= N) return;
  int beg_ = beg[node], end_ = beg_ + counts[node];
  bool b4 = (lane & 16) != 0, b5 = (lane & 32) != 0;   // head = lane>>4

  float4 adv4 = *reinterpret_cast<const float4*>(ad1 + (size_t)node*4);
  float adv[4] = {adv4.x, adv4.y, adv4.z, adv4.w};
  float4 sv4 = *reinterpret_cast<const float4*>(as1 + (size_t)node*4);
  float svv[4] = {sv4.x, sv4.y, sv4.z, sv4.w};

  float es[4], m[4], sp[4];
  #pragma unroll
  for (int k = 0; k < 4; k++){
    es[k] = lrelu(svv[k] + adv[k]);   // self-loop logit
    m[k] = es[k];                     // running max init
    sp[k] = 0.f;                      // per-lane partial sum of exp
  }
  float4 acc = make_float4(0.f, 0.f, 0.f, 0.f);

  for (int base = beg_; base < end_; base += 64){
    int i = base + lane;
    bool val = i < end_;
    int srcl = val ? adj[i] : 0;
    float4 av4 = *reinterpret_cast<const float4*>(as1 + (size_t)srcl*4);
    float e[4] = {av4.x, av4.y, av4.z, av4.w};
    #pragma unroll
    for (int k = 0; k < 4; k++) e[k] = val ? lrelu(e[k] + adv[k]) : -3e38f;

    // chunk max + online rescale
    float sc[4];
    #pragma unroll
    for (int k = 0; k < 4; k++){
      float cm = e[k];
      #pragma unroll
      for (int off = 32; off; off >>= 1) cm = fmaxf(cm, __shfl_xor(cm, off, 64));
      float nm = fmaxf(m[k], cm);
      sc[k] = __expf(m[k] - nm);
      m[k] = nm;
      sp[k] *= sc[k];
    }
    float sch = selh(sc[0], sc[1], sc[2], sc[3], b4, b5);
    acc.x *= sch; acc.y *= sch; acc.z *= sch; acc.w *= sch;

    // per-edge exp computed ONCE (lane-parallel over edges)
    float ex[4];
    #pragma unroll
    for (int k = 0; k < 4; k++){
      ex[k] = __expf(e[k] - m[k]);    // invalid lanes: exp(-huge) -> 0
      sp[k] += ex[k];
    }

    // broadcast phase: readlane weights, bf16x4 (uint2) gather of h1[src]
    int cnt = end_ - base; if (cnt > 64) cnt = 64;
    #pragma unroll 2
    for (int j = 0; j < cnt; j++){
      int srcj = __builtin_amdgcn_readlane(srcl, j);
      float e0 = rl(ex[0], j), e1 = rl(ex[1], j);
      float e2 = rl(ex[2], j), e3 = rl(ex[3], j);
      float eh = selh(e0, e1, e2, e3, b4, b5);
      uint2 hv = *reinterpret_cast<const uint2*>(h1b + (size_t)srcj*256 + lane*4);
      float h0 = __uint_as_float(hv.x << 16);
      float h1v = __uint_as_float(hv.x & 0xffff0000u);
      float h2v = __uint_as_float(hv.y << 16);
      float h3v = __uint_as_float(hv.y & 0xffff0000u);
      acc.x = fmaf(eh, h0,  acc.x);
      acc.y = fmaf(eh, h1v, acc.y);
      acc.z = fmaf(eh, h2v, acc.z);
      acc.w = fmaf(eh, h3v, acc.w);
    }
  }

  // total denominator per head
  #pragma unroll
  for (int k = 0; k < 4; k++){
    #pragma unroll
    for (int off = 32; off; off >>= 1) sp[k] += __shfl_xor(sp[k], off, 64);
  }
  // self-loop contribution
  float exs[4];
  #pragma unroll
  for (int k = 0; k < 4; k++){
    exs[k] = __expf(es[k] - m[k]);
    sp[k] += exs[k];
  }
  float ehs = selh(exs[0], exs[1], exs[2], exs[3], b4, b5);
  uint2 hv = *reinterpret_cast<const uint2*>(h1b + (size_t)node*256 + lane*4);
  acc.x = fmaf(ehs, __uint_as_float(hv.x << 16),        acc.x);
  acc.y = fmaf(ehs, __uint_as_float(hv.x & 0xffff0000u), acc.y);
  acc.z = fmaf(ehs, __uint_as_float(hv.y << 16),        acc.z);
  acc.w = fmaf(ehs, __uint_as_float(hv.y & 0xffff0000u), acc.w);

  float dh = selh(sp[0], sp[1], sp[2], sp[3], b4, b5) + 1e-16f;
  float rinv = 1.0f / dh;
  float4 bv = *reinterpret_cast<const float4*>(b1 + lane*4);
  float4 o;
  o.x = acc.x*rinv + bv.x;
  o.y = acc.y*rinv + bv.y;
  o.z = acc.z*rinv + bv.z;
  o.w = acc.w*rinv + bv.w;
  o.x = o.x > 0.f ? o.x : expm1f(o.x);
  o.y = o.y > 0.f ? o.y : expm1f(o.y);
  o.z = o.z > 0.f ? o.z : expm1f(o.z);
  o.w = o.w > 0.f ? o.w : expm1f(o.w);
  *reinterpret_cast<float4*>(hact + (size_t)node*256 + lane*4) = o;
}

// ---- GEMM2: h2 = hact @ W2  [N,256]x[256,16], fused alpha_src2/alpha_dst2 ----
__global__ void gemm2_kernel(const float* __restrict__ hact, const float* __restrict__ W2,
                             const float* __restrict__ asrc, const float* __restrict__ adst,
                             float* __restrict__ h2, float* __restrict__ as2,
                             float* __restrict__ ad2){
  __shared__ float a_s[16][260];
  __shared__ float w_s[256*16];
  int t = threadIdx.x;
  int row0 = blockIdx.x * 16;
  for (int i = t; i < 1024; i += 256)
    reinterpret_cast<float4*>(w_s)[i] = reinterpret_cast<const float4*>(W2)[i];
  const float4* hv = reinterpret_cast<const float4*>(hact + (size_t)row0 * 256);
  for (int i = t; i < 1024; i += 256){
    int r = i >> 6, j = i & 63;
    *reinterpret_cast<float4*>(&a_s[r][j*4]) = hv[(size_t)r*64 + j];
  }
  __syncthreads();
  int r = t >> 4, c = t & 15;
  float acc = 0.f;
  #pragma unroll 4
  for (int k = 0; k < 256; k++) acc = fmaf(a_s[r][k], w_s[k*16 + c], acc);
  int node = row0 + r;
  h2[(size_t)node*16 + c] = acc;
  float ps = acc * asrc[c], pd = acc * adst[c];
  #pragma unroll
  for (int off = 1; off < 16; off <<= 1){
    ps += __shfl_xor(ps, off, 64);
    pd += __shfl_xor(pd, off, 64);
  }
  if (c == 0){ as2[node] = ps; ad2[node] = pd; }
}

// ---- layer-2 aggregation: wave per node (4 edge-groups x 16 channels), fused bias+log_softmax ----
__global__ void agg2_kernel(const float* __restrict__ h2, const float* __restrict__ as2,
                            const float* __restrict__ ad2, const float* __restrict__ b2,
                            const int* __restrict__ beg, const int* __restrict__ counts,
                            const int* __restrict__ adj,
                            float* __restrict__ out, int N){
  int node = (blockIdx.x*blockDim.x + threadIdx.x) >> 6;
  int lane = threadIdx.x & 63;
  if (node >= N) return;
  int beg_ = beg[node], end_ = beg_ + counts[node];
  float adn = ad2[node];
  float m = -1e30f;
  for (int i = beg_ + lane; i < end_; i += 64)
    m = fmaxf(m, lrelu(as2[adj[i]] + adn));
  float eself = lrelu(as2[node] + adn);
  m = fmaxf(m, eself);
  #pragma unroll
  for (int off = 32; off; off >>= 1) m = fmaxf(m, __shfl_xor(m, off, 64));
  int g = lane >> 4, c = lane & 15;
  float s = 0.f, acc = 0.f;
  for (int i = beg_ + g; i < end_; i += 4){
    int src = adj[i];
    float ex = __expf(lrelu(as2[src] + adn) - m);
    s += ex;
    acc = fmaf(ex, h2[(size_t)src*16 + c], acc);
  }
  if (g == 0){
    float ex = __expf(eself - m);
    s += ex;
    acc = fmaf(ex, h2[(size_t)node*16 + c], acc);
  }
  acc += __shfl_xor(acc, 16, 64); acc += __shfl_xor(acc, 32, 64);
  s   += __shfl_xor(s,   16, 64); s   += __shfl_xor(s,   32, 64);
  float v = acc / (s + 1e-16f) + b2[c];
  // log_softmax over the 16 channels (replicated identically in each 16-lane group)
  float mx = v;
  #pragma unroll
  for (int off = 1; off < 16; off <<= 1) mx = fmaxf(mx, __shfl_xor(mx, off, 64));
  float se = expf(v - mx);
  #pragma unroll
  for (int off = 1; off < 16; off <<= 1) se += __shfl_xor(se, off, 64);
  float o = v - mx - logf(se);
  if (lane < 16) out[(size_t)node*16 + c] = o;
}

extern "C" void kernel_launch(void* const* d_in, const int* in_sizes, int n_in,
                              void* d_out, int out_size, void* d_ws, size_t ws_size,
                              hipStream_t stream){
  const float* x    = (const float*)d_in[0];
  const int*   ei   = (const int*)d_in[1];
  const float* W1   = (const float*)d_in[2];
  const float* as1w = (const float*)d_in[3];
  const float* ad1w = (const float*)d_in[4];
  const float* b1   = (const float*)d_in[5];
  const float* W2   = (const float*)d_in[6];
  const float* as2w = (const float*)d_in[7];
  const float* ad2w = (const float*)d_in[8];
  const float* b2   = (const float*)d_in[9];
  float* out = (float*)d_out;

  int N = in_sizes[0] / 128;   // 50000
  int E = in_sizes[1] / 2;     // 800000 (element count same for int32/int64)

  char* p = (char*)d_ws;
  size_t off = 0;
  auto alloc = [&](size_t b){ size_t c = off; off = (off + b + 255) & ~(size_t)255; return c; };
  unsigned short* h1b = (unsigned short*)(p + alloc((size_t)N*256*2)); // 25.6 MB bf16
  float* hact   = (float*)(p + alloc((size_t)N*256*4));   // 51.2 MB
  float* h2     = (float*)(p + alloc((size_t)N*16*4));    // 3.2 MB
  float* as1    = (float*)(p + alloc((size_t)N*4*4));
  float* ad1    = (float*)(p + alloc((size_t)N*4*4));
  float* as2    = (float*)(p + alloc((size_t)N*4));
  float* ad2    = (float*)(p + alloc((size_t)N*4));
  int*   counts = (int*)(p + alloc((size_t)N*4));
  int*   beg    = (int*)(p + alloc((size_t)N*4));
  int*   cursor = (int*)(p + alloc((size_t)N*4));
  int*   adj    = (int*)(p + alloc((size_t)E*4));         // 3.2 MB
  int*   flag   = (int*)(p + alloc(4));
  int*   totalCtr = (int*)(p + alloc(4));

  hipMemsetAsync(counts, 0, (size_t)N*4, stream);
  hipMemsetAsync(totalCtr, 0, 4, stream);
  detect_kernel<<<1, 64, 0, stream>>>(ei, flag);
  count_kernel<<<2048, 256, 0, stream>>>(ei, flag, counts, E);
  assign_kernel<<<(N + 255)/256, 256, 0, stream>>>(counts, beg, cursor, totalCtr, N);
  fill_kernel<<<2048, 256, 0, stream>>>(ei, flag, cursor, adj, E);

  gemm1_kernel<<<N/16, 256, 0, stream>>>(x, W1, as1w, ad1w, h1b, as1, ad1);
  agg1_kernel<<<(N*64 + 255)/256, 256, 0, stream>>>(h1b, as1, ad1, b1, beg, counts, adj, hact, N);
  gemm2_kernel<<<N/16, 256, 0, stream>>>(hact, W2, as2w, ad2w, h2, as2, ad2);
  agg2_kernel<<<(N*64 + 255)/256, 256, 0, stream>>>(h2, as2, ad2, b2, beg, counts, adj, out, N);
}

// Round 4
// 293.385 us; speedup vs baseline: 1.5125x; 1.1576x over previous
//
#include <hip/hip_runtime.h>
#include <math.h>

#define NEG 0.2f

typedef __attribute__((ext_vector_type(8))) short bf16x8;
typedef __attribute__((ext_vector_type(4))) float f32x4;

__device__ __forceinline__ float lrelu(float x){ return x > 0.f ? x : NEG*x; }

__device__ __forceinline__ float rl(float x, int j){
  return __uint_as_float((unsigned)__builtin_amdgcn_readlane((int)__float_as_uint(x), j));
}

// select a0..a3 by head index encoded in (b4,b5) = (lane&16, lane&32)
__device__ __forceinline__ float selh(float a0, float a1, float a2, float a3,
                                      bool b4, bool b5){
  float lo = b4 ? a1 : a0;
  float hi = b4 ? a3 : a2;
  return b5 ? hi : lo;
}

__device__ __forceinline__ unsigned short f2bf(float x){
  unsigned u = __float_as_uint(x);
  u += 0x7fffu + ((u >> 16) & 1u);     // RNE
  return (unsigned short)(u >> 16);
}

// ---- detect whether edge_index is int64 (odd 32-bit words all zero) or int32 ----
__global__ void detect_kernel(const int* __restrict__ ei, int* __restrict__ flag){
  int lane = threadIdx.x;                 // 64 threads, 1 block
  int v = ei[2*lane + 1];
  unsigned long long b = __ballot(v != 0);
  if (lane == 0) flag[0] = (b == 0ULL) ? 1 : 0;   // 1 => int64 layout
}

__global__ void count_kernel(const int* __restrict__ ei, const int* __restrict__ flag,
                             int* __restrict__ counts, int E){
  int is64 = flag[0];
  int stride = gridDim.x * blockDim.x;
  for (int i = blockIdx.x*blockDim.x + threadIdx.x; i < E; i += stride){
    int d = is64 ? ei[2*(E + i)] : ei[E + i];
    atomicAdd(&counts[d], 1);
  }
}

// ---- parallel segment assignment: no ordered prefix sum needed for CSR ----
__global__ void assign_kernel(const int* __restrict__ counts, int* __restrict__ beg,
                              int* __restrict__ cursor, int* __restrict__ totalCtr, int n){
  int i = blockIdx.x*blockDim.x + threadIdx.x;
  if (i < n){
    int c = counts[i];
    int b = atomicAdd(totalCtr, c);
    beg[i] = b;
    cursor[i] = b;
  }
}

__global__ void fill_kernel(const int* __restrict__ ei, const int* __restrict__ flag,
                            int* __restrict__ cursor, int* __restrict__ adj, int E){
  int is64 = flag[0];
  int stride = gridDim.x * blockDim.x;
  for (int i = blockIdx.x*blockDim.x + threadIdx.x; i < E; i += stride){
    int s = is64 ? ei[2*i]       : ei[i];
    int d = is64 ? ei[2*(E + i)] : ei[E + i];
    int pos = atomicAdd(&cursor[d], 1);
    adj[pos] = s;
  }
}

// ---- GEMM1 via MFMA: h1b = bf16(x @ W1)  [N,128]x[128,256] ----
// W1 transposed->bf16 in LDS (64KB, XOR-swizzled k-groups, conflict-free b128).
// Wave w computes rows blockIdx*64 + w*16 .. +15, all 256 cols, K=128.
__device__ __forceinline__ int wt_addr(int col, int k){   // address in shorts
  int g = (k >> 3) ^ (col & 7);
  return col*128 + g*8 + (k & 7);
}

__global__ __launch_bounds__(256) void gemm1_mfma(const float* __restrict__ x,
                             const float* __restrict__ W,
                             unsigned short* __restrict__ h1b, int N){
  __shared__ unsigned short wt[256*128];   // 65536 B
  int t = threadIdx.x;
  int lane = t & 63, w = t >> 6;
  int row0 = blockIdx.x * 64 + w * 16;

  // A-frags from x (before staging barrier): row = lane&15, k = (lane>>4)*8 + j
  int arow = row0 + (lane & 15);
  if (arow >= N) arow = N - 1;
  const float* xr = x + (size_t)arow * 128 + (lane >> 4) * 8;
  bf16x8 afrag[4];
  #pragma unroll
  for (int kk = 0; kk < 4; kk++){
    float4 p0 = *reinterpret_cast<const float4*>(xr + kk*32);
    float4 p1 = *reinterpret_cast<const float4*>(xr + kk*32 + 4);
    afrag[kk][0] = (short)f2bf(p0.x); afrag[kk][1] = (short)f2bf(p0.y);
    afrag[kk][2] = (short)f2bf(p0.z); afrag[kk][3] = (short)f2bf(p0.w);
    afrag[kk][4] = (short)f2bf(p1.x); afrag[kk][5] = (short)f2bf(p1.y);
    afrag[kk][6] = (short)f2bf(p1.z); afrag[kk][7] = (short)f2bf(p1.w);
  }

  // stage W1 transposed: thread t owns col c=t; coalesced global reads
  int c = t;
  for (int k0 = 0; k0 < 128; k0 += 8){
    bf16x8 v;
    #pragma unroll
    for (int j = 0; j < 8; j++) v[j] = (short)f2bf(W[(size_t)(k0+j)*256 + c]);
    *reinterpret_cast<bf16x8*>(&wt[wt_addr(c, k0)]) = v;
  }
  __syncthreads();

  f32x4 acc[16];
  #pragma unroll
  for (int n = 0; n < 16; n++) acc[n] = (f32x4){0.f,0.f,0.f,0.f};
  #pragma unroll
  for (int kk = 0; kk < 4; kk++){
    #pragma unroll
    for (int n = 0; n < 16; n++){
      bf16x8 b = *reinterpret_cast<const bf16x8*>(
          &wt[wt_addr(n*16 + (lane & 15), kk*32 + (lane >> 4)*8)]);
      acc[n] = __builtin_amdgcn_mfma_f32_16x16x32_bf16(afrag[kk], b, acc[n], 0, 0, 0);
    }
  }

  // store: row = row0 + (lane>>4)*4 + r, col = n*16 + (lane&15)
  int rbase = row0 + (lane >> 4)*4;
  int cbase = lane & 15;
  #pragma unroll
  for (int n = 0; n < 16; n++){
    #pragma unroll
    for (int r = 0; r < 4; r++){
      int row = rbase + r;
      if (row < N) h1b[(size_t)row*256 + n*16 + cbase] = f2bf(acc[n][r]);
    }
  }
}

// ---- alpha1: as1/ad1[node][head] = sum_ch h1[node][head*64+ch] * a[head][ch] ----
__global__ void alpha1_kernel(const unsigned short* __restrict__ h1b,
                              const float* __restrict__ asrc, const float* __restrict__ adst,
                              float* __restrict__ as1, float* __restrict__ ad1, int N){
  int node = (blockIdx.x*blockDim.x + threadIdx.x) >> 6;
  int lane = threadIdx.x & 63;
  if (node >= N) return;
  uint2 hv = *reinterpret_cast<const uint2*>(h1b + (size_t)node*256 + lane*4);
  float h0 = __uint_as_float(hv.x << 16);
  float h1 = __uint_as_float(hv.x & 0xffff0000u);
  float h2 = __uint_as_float(hv.y << 16);
  float h3 = __uint_as_float(hv.y & 0xffff0000u);
  int head = lane >> 4, ch = (lane & 15)*4;
  float4 av = *reinterpret_cast<const float4*>(asrc + head*64 + ch);
  float4 dv = *reinterpret_cast<const float4*>(adst + head*64 + ch);
  float ps = h0*av.x + h1*av.y + h2*av.z + h3*av.w;
  float pd = h0*dv.x + h1*dv.y + h2*dv.z + h3*dv.w;
  #pragma unroll
  for (int off = 1; off < 16; off <<= 1){
    ps += __shfl_xor(ps, off, 64);
    pd += __shfl_xor(pd, off, 64);
  }
  if ((lane & 15) == 0){
    as1[node*4 + head] = ps;
    ad1[node*4 + head] = pd;
  }
}

// ---- layer-1 aggregation: wave per dst node, online softmax, bf16 h1 gather ----
__global__ void agg1_kernel(const unsigned short* __restrict__ h1b,
                            const float* __restrict__ as1,
                            const float* __restrict__ ad1, const float* __restrict__ b1,
                            const int* __restrict__ beg, const int* __restrict__ counts,
                            const int* __restrict__ adj,
                            float* __restrict__ hact, int N){
  int node = (blockIdx.x*blockDim.x + threadIdx.x) >> 6;
  int lane = threadIdx.x & 63;
  if (node >= N) return;
  int beg_ = beg[node], end_ = beg_ + counts[node];
  bool b4 = (lane & 16) != 0, b5 = (lane & 32) != 0;   // head = lane>>4

  float4 adv4 = *reinterpret_cast<const float4*>(ad1 + (size_t)node*4);
  float adv[4] = {adv4.x, adv4.y, adv4.z, adv4.w};
  float4 sv4 = *reinterpret_cast<const float4*>(as1 + (size_t)node*4);
  float svv[4] = {sv4.x, sv4.y, sv4.z, sv4.w};

  float es[4], m[4], sp[4];
  #pragma unroll
  for (int k = 0; k < 4; k++){
    es[k] = lrelu(svv[k] + adv[k]);   // self-loop logit
    m[k] = es[k];                     // running max init
    sp[k] = 0.f;                      // per-lane partial sum of exp
  }
  float4 acc = make_float4(0.f, 0.f, 0.f, 0.f);

  for (int base = beg_; base < end_; base += 64){
    int i = base + lane;
    bool val = i < end_;
    int srcl = val ? adj[i] : 0;
    float4 av4 = *reinterpret_cast<const float4*>(as1 + (size_t)srcl*4);
    float e[4] = {av4.x, av4.y, av4.z, av4.w};
    #pragma unroll
    for (int k = 0; k < 4; k++) e[k] = val ? lrelu(e[k] + adv[k]) : -3e38f;

    // chunk max + online rescale
    float sc[4];
    #pragma unroll
    for (int k = 0; k < 4; k++){
      float cm = e[k];
      #pragma unroll
      for (int off = 32; off; off >>= 1) cm = fmaxf(cm, __shfl_xor(cm, off, 64));
      float nm = fmaxf(m[k], cm);
      sc[k] = __expf(m[k] - nm);
      m[k] = nm;
      sp[k] *= sc[k];
    }
    float sch = selh(sc[0], sc[1], sc[2], sc[3], b4, b5);
    acc.x *= sch; acc.y *= sch; acc.z *= sch; acc.w *= sch;

    // per-edge exp computed ONCE (lane-parallel over edges)
    float ex[4];
    #pragma unroll
    for (int k = 0; k < 4; k++){
      ex[k] = __expf(e[k] - m[k]);    // invalid lanes: exp(-huge) -> 0
      sp[k] += ex[k];
    }

    // broadcast phase: readlane weights, bf16x4 (uint2) gather of h1[src]
    int cnt = end_ - base; if (cnt > 64) cnt = 64;
    #pragma unroll 2
    for (int j = 0; j < cnt; j++){
      int srcj = __builtin_amdgcn_readlane(srcl, j);
      float e0 = rl(ex[0], j), e1 = rl(ex[1], j);
      float e2 = rl(ex[2], j), e3 = rl(ex[3], j);
      float eh = selh(e0, e1, e2, e3, b4, b5);
      uint2 hv = *reinterpret_cast<const uint2*>(h1b + (size_t)srcj*256 + lane*4);
      float h0 = __uint_as_float(hv.x << 16);
      float h1v = __uint_as_float(hv.x & 0xffff0000u);
      float h2v = __uint_as_float(hv.y << 16);
      float h3v = __uint_as_float(hv.y & 0xffff0000u);
      acc.x = fmaf(eh, h0,  acc.x);
      acc.y = fmaf(eh, h1v, acc.y);
      acc.z = fmaf(eh, h2v, acc.z);
      acc.w = fmaf(eh, h3v, acc.w);
    }
  }

  // total denominator per head
  #pragma unroll
  for (int k = 0; k < 4; k++){
    #pragma unroll
    for (int off = 32; off; off >>= 1) sp[k] += __shfl_xor(sp[k], off, 64);
  }
  // self-loop contribution
  float exs[4];
  #pragma unroll
  for (int k = 0; k < 4; k++){
    exs[k] = __expf(es[k] - m[k]);
    sp[k] += exs[k];
  }
  float ehs = selh(exs[0], exs[1], exs[2], exs[3], b4, b5);
  uint2 hv = *reinterpret_cast<const uint2*>(h1b + (size_t)node*256 + lane*4);
  acc.x = fmaf(ehs, __uint_as_float(hv.x << 16),        acc.x);
  acc.y = fmaf(ehs, __uint_as_float(hv.x & 0xffff0000u), acc.y);
  acc.z = fmaf(ehs, __uint_as_float(hv.y << 16),        acc.z);
  acc.w = fmaf(ehs, __uint_as_float(hv.y & 0xffff0000u), acc.w);

  float dh = selh(sp[0], sp[1], sp[2], sp[3], b4, b5) + 1e-16f;
  float rinv = 1.0f / dh;
  float4 bv = *reinterpret_cast<const float4*>(b1 + lane*4);
  float4 o;
  o.x = acc.x*rinv + bv.x;
  o.y = acc.y*rinv + bv.y;
  o.z = acc.z*rinv + bv.z;
  o.w = acc.w*rinv + bv.w;
  o.x = o.x > 0.f ? o.x : expm1f(o.x);
  o.y = o.y > 0.f ? o.y : expm1f(o.y);
  o.z = o.z > 0.f ? o.z : expm1f(o.z);
  o.w = o.w > 0.f ? o.w : expm1f(o.w);
  *reinterpret_cast<float4*>(hact + (size_t)node*256 + lane*4) = o;
}

// ---- GEMM2: h2 = hact @ W2  [N,256]x[256,16], fused alpha_src2/alpha_dst2 ----
__global__ void gemm2_kernel(const float* __restrict__ hact, const float* __restrict__ W2,
                             const float* __restrict__ asrc, const float* __restrict__ adst,
                             float* __restrict__ h2, float* __restrict__ as2,
                             float* __restrict__ ad2){
  __shared__ float a_s[16][260];
  __shared__ float w_s[256*16];
  int t = threadIdx.x;
  int row0 = blockIdx.x * 16;
  for (int i = t; i < 1024; i += 256)
    reinterpret_cast<float4*>(w_s)[i] = reinterpret_cast<const float4*>(W2)[i];
  const float4* hv = reinterpret_cast<const float4*>(hact + (size_t)row0 * 256);
  for (int i = t; i < 1024; i += 256){
    int r = i >> 6, j = i & 63;
    *reinterpret_cast<float4*>(&a_s[r][j*4]) = hv[(size_t)r*64 + j];
  }
  __syncthreads();
  int r = t >> 4, c = t & 15;
  float acc = 0.f;
  #pragma unroll 4
  for (int k = 0; k < 256; k++) acc = fmaf(a_s[r][k], w_s[k*16 + c], acc);
  int node = row0 + r;
  h2[(size_t)node*16 + c] = acc;
  float ps = acc * asrc[c], pd = acc * adst[c];
  #pragma unroll
  for (int off = 1; off < 16; off <<= 1){
    ps += __shfl_xor(ps, off, 64);
    pd += __shfl_xor(pd, off, 64);
  }
  if (c == 0){ as2[node] = ps; ad2[node] = pd; }
}

// ---- layer-2 aggregation: wave per node (4 edge-groups x 16 channels), fused bias+log_softmax ----
__global__ void agg2_kernel(const float* __restrict__ h2, const float* __restrict__ as2,
                            const float* __restrict__ ad2, const float* __restrict__ b2,
                            const int* __restrict__ beg, const int* __restrict__ counts,
                            const int* __restrict__ adj,
                            float* __restrict__ out, int N){
  int node = (blockIdx.x*blockDim.x + threadIdx.x) >> 6;
  int lane = threadIdx.x & 63;
  if (node >= N) return;
  int beg_ = beg[node], end_ = beg_ + counts[node];
  float adn = ad2[node];
  float m = -1e30f;
  for (int i = beg_ + lane; i < end_; i += 64)
    m = fmaxf(m, lrelu(as2[adj[i]] + adn));
  float eself = lrelu(as2[node] + adn);
  m = fmaxf(m, eself);
  #pragma unroll
  for (int off = 32; off; off >>= 1) m = fmaxf(m, __shfl_xor(m, off, 64));
  int g = lane >> 4, c = lane & 15;
  float s = 0.f, acc = 0.f;
  for (int i = beg_ + g; i < end_; i += 4){
    int src = adj[i];
    float ex = __expf(lrelu(as2[src] + adn) - m);
    s += ex;
    acc = fmaf(ex, h2[(size_t)src*16 + c], acc);
  }
  if (g == 0){
    float ex = __expf(eself - m);
    s += ex;
    acc = fmaf(ex, h2[(size_t)node*16 + c], acc);
  }
  acc += __shfl_xor(acc, 16, 64); acc += __shfl_xor(acc, 32, 64);
  s   += __shfl_xor(s,   16, 64); s   += __shfl_xor(s,   32, 64);
  float v = acc / (s + 1e-16f) + b2[c];
  // log_softmax over the 16 channels (replicated identically in each 16-lane group)
  float mx = v;
  #pragma unroll
  for (int off = 1; off < 16; off <<= 1) mx = fmaxf(mx, __shfl_xor(mx, off, 64));
  float se = expf(v - mx);
  #pragma unroll
  for (int off = 1; off < 16; off <<= 1) se += __shfl_xor(se, off, 64);
  float o = v - mx - logf(se);
  if (lane < 16) out[(size_t)node*16 + c] = o;
}

extern "C" void kernel_launch(void* const* d_in, const int* in_sizes, int n_in,
                              void* d_out, int out_size, void* d_ws, size_t ws_size,
                              hipStream_t stream){
  const float* x    = (const float*)d_in[0];
  const int*   ei   = (const int*)d_in[1];
  const float* W1   = (const float*)d_in[2];
  const float* as1w = (const float*)d_in[3];
  const float* ad1w = (const float*)d_in[4];
  const float* b1   = (const float*)d_in[5];
  const float* W2   = (const float*)d_in[6];
  const float* as2w = (const float*)d_in[7];
  const float* ad2w = (const float*)d_in[8];
  const float* b2   = (const float*)d_in[9];
  float* out = (float*)d_out;

  int N = in_sizes[0] / 128;   // 50000
  int E = in_sizes[1] / 2;     // 800000 (element count same for int32/int64)

  char* p = (char*)d_ws;
  size_t off = 0;
  auto alloc = [&](size_t b){ size_t c = off; off = (off + b + 255) & ~(size_t)255; return c; };
  unsigned short* h1b = (unsigned short*)(p + alloc((size_t)N*256*2)); // 25.6 MB bf16
  float* hact   = (float*)(p + alloc((size_t)N*256*4));   // 51.2 MB
  float* h2     = (float*)(p + alloc((size_t)N*16*4));    // 3.2 MB
  float* as1    = (float*)(p + alloc((size_t)N*4*4));
  float* ad1    = (float*)(p + alloc((size_t)N*4*4));
  float* as2    = (float*)(p + alloc((size_t)N*4));
  float* ad2    = (float*)(p + alloc((size_t)N*4));
  int*   counts = (int*)(p + alloc((size_t)N*4));
  int*   beg    = (int*)(p + alloc((size_t)N*4));
  int*   cursor = (int*)(p + alloc((size_t)N*4));
  int*   adj    = (int*)(p + alloc((size_t)E*4));         // 3.2 MB
  int*   flag   = (int*)(p + alloc(4));
  int*   totalCtr = (int*)(p + alloc(4));

  hipMemsetAsync(counts, 0, (size_t)N*4, stream);
  hipMemsetAsync(totalCtr, 0, 4, stream);
  detect_kernel<<<1, 64, 0, stream>>>(ei, flag);
  count_kernel<<<2048, 256, 0, stream>>>(ei, flag, counts, E);
  assign_kernel<<<(N + 255)/256, 256, 0, stream>>>(counts, beg, cursor, totalCtr, N);
  fill_kernel<<<2048, 256, 0, stream>>>(ei, flag, cursor, adj, E);

  gemm1_mfma<<<(N + 63)/64, 256, 0, stream>>>(x, W1, h1b, N);
  alpha1_kernel<<<(N*64 + 255)/256, 256, 0, stream>>>(h1b, as1w, ad1w, as1, ad1, N);
  agg1_kernel<<<(N*64 + 255)/256, 256, 0, stream>>>(h1b, as1, ad1, b1, beg, counts, adj, hact, N);
  gemm2_kernel<<<N/16, 256, 0, stream>>>(hact, W2, as2w, ad2w, h2, as2, ad2);
  agg2_kernel<<<(N*64 + 255)/256, 256, 0, stream>>>(h2, as2, ad2, b2, beg, counts, adj, out, N);
}